// Round 1
// baseline (2103.686 us; speedup 1.0000x reference)
//
#include <hip/hip_runtime.h>

// Lee oscillator, 99 recurrence steps, elementwise over 4096x4096 f32.
// Chaotic 1-D map per element => must replicate XLA's float32 op sequence
// BITWISE. tanh = XLA EmitFastTanh (Eigen rational approx, with_fma=true):
//   clamp +-7.99881172180175781, Horner with fused FMA, IEEE f32 division,
//   |x| < 0.0004 -> x passthrough.
// All other ops: single-rounded mul/add/sub in the reference's left-assoc
// order; fp contract OFF so the backend cannot fuse them.

#pragma clang fp contract(off)

#define N_ITERS 99  // N_STEPS - 1

// (a1,a2,a3,a4, b1,b2,b3,b4, xi_E, xi_I) for oscillator types 1..8
__device__ __constant__ float kCoeffs[8][10] = {
    { 0.0f,  5.0f,   5.0f,   1.0f,  0.0f, -1.0f,   1.0f,  0.0f, 0.0f, 0.0f},
    { 0.5f,  0.55f,  0.55f, -0.5f,  0.5f, -0.55f, -0.55f, -0.5f, 0.0f, 0.0f},
    {-5.0f,  5.0f,   5.0f,  -5.0f,  1.0f, -1.0f,  -1.0f,  1.0f, 0.0f, 0.0f},
    { 1.0f,  1.0f,   1.0f,  -1.0f, -1.0f, -1.0f,  -1.0f,  1.0f, 0.0f, 0.0f},
    { 5.0f, -5.0f,  -5.0f,   5.0f, -1.0f,  1.0f,   1.0f, -1.0f, 0.0f, 0.0f},
    {-1.0f, -1.0f,  -1.0f,   1.0f,  1.0f,  1.0f,   1.0f, -1.0f, 0.0f, 0.0f},
    { 1.0f, -1.0f,  -1.0f,   1.0f, -1.0f,  1.0f,   1.0f, -1.0f, 0.0f, 0.0f},
    {-1.0f,  1.0f,   1.0f,  -1.0f,  1.0f, -1.0f,  -1.0f,  1.0f, 0.0f, 0.0f},
};

// XLA EmitFastTanh / Eigen generic_fast_tanh_float, with_fma variant.
// Every op correctly rounded -> bitwise reproducible across backends.
__device__ __forceinline__ float xla_fast_tanh(float x) {
#pragma clang fp contract(off)
    const float kClamp = 7.99881172180175781f;  // with_fma clamp
    float ax = __builtin_fabsf(x);
    float xc = __builtin_fminf(__builtin_fmaxf(x, -kClamp), kClamp);
    float x2 = __fmul_rn(xc, xc);
    float p = __fmaf_rn(x2, -2.76076847742355e-16f, 2.00018790482477e-13f);
    p = __fmaf_rn(x2, p, -8.60467152213735e-11f);
    p = __fmaf_rn(x2, p, 5.12229709037114e-08f);
    p = __fmaf_rn(x2, p, 1.48572235717979e-05f);
    p = __fmaf_rn(x2, p, 6.37261928875436e-04f);
    p = __fmaf_rn(x2, p, 4.89352455891786e-03f);
    p = __fmul_rn(xc, p);
    float q = __fmaf_rn(x2, 1.19825839466702e-06f, 1.18534705686654e-04f);
    q = __fmaf_rn(x2, q, 2.26843463243900e-03f);
    q = __fmaf_rn(x2, q, 4.89352518554385e-03f);
    float r = p / q;  // IEEE-correct f32 division (default hipcc, no fast-math)
    return (ax < 0.0004f) ? x : r;
}

__global__ __launch_bounds__(256) void lee_osc_kernel(
    const float* __restrict__ x, const int* __restrict__ osc_type,
    float* __restrict__ out, int n) {
#pragma clang fp contract(off)
    int i = blockIdx.x * blockDim.x + threadIdx.x;
    if (i >= n) return;

    int t = osc_type[0];  // uniform across grid
    if (t < 1 || t > 8) t = 1;
    const float* c = kCoeffs[t - 1];
    const float a1 = c[0], a2 = c[1], a3 = c[2], a4 = c[3];
    const float b1 = c[4], b2 = c[5], b3 = c[6], b4 = c[7];
    const float xiE = c[8], xiI = c[9];

    float xv = x[i];
    // jnp.sign
    float sgn = (xv > 0.0f) ? 1.0f : ((xv < 0.0f) ? -1.0f : 0.0f);
    // sim = x + 0.001*sign(x)
    float sim = __fadd_rn(xv, __fmul_rn(0.001f, sgn));
    // gate = exp((-500*sim)*sim) — enters only linearly for type 1, ~1ulp ok
    float gq = __fmul_rn(__fmul_rn(-500.0f, sim), sim);
    float gate = expf(gq);
    // omega = tanh(5*sim) — constant, linear contribution
    float omega = xla_fast_tanh(__fmul_rn(5.0f, sim));

    float E = 0.2f, I = 0.0f, L = 0.2f;
    for (int s = 0; s < N_ITERS; ++s) {
        // E1 = tanh(5 * ((((a1*L + a2*E) - a3*I) + a4*sim) - xiE))
        float tE = __fmul_rn(a1, L);
        tE = __fadd_rn(tE, __fmul_rn(a2, E));
        tE = __fsub_rn(tE, __fmul_rn(a3, I));
        tE = __fadd_rn(tE, __fmul_rn(a4, sim));
        tE = __fsub_rn(tE, xiE);
        float E1 = xla_fast_tanh(__fmul_rn(5.0f, tE));

        // I1 = tanh(5 * ((((b1*L - b2*E) - b3*I) + b4*sim) - xiI))
        float tI = __fmul_rn(b1, L);
        tI = __fsub_rn(tI, __fmul_rn(b2, E));
        tI = __fsub_rn(tI, __fmul_rn(b3, I));
        tI = __fadd_rn(tI, __fmul_rn(b4, sim));
        tI = __fsub_rn(tI, xiI);
        float I1 = xla_fast_tanh(__fmul_rn(5.0f, tI));

        // L = (E1 - I1)*gate + omega   (mul then add, NOT fma)
        L = __fadd_rn(__fmul_rn(__fsub_rn(E1, I1), gate), omega);
        E = E1;
        I = I1;
    }
    out[i] = L;
}

extern "C" void kernel_launch(void* const* d_in, const int* in_sizes, int n_in,
                              void* d_out, int out_size, void* d_ws, size_t ws_size,
                              hipStream_t stream) {
    const float* x = (const float*)d_in[0];
    const int* typ = (const int*)d_in[1];
    float* out = (float*)d_out;
    int n = out_size;
    int threads = 256;
    int blocks = (n + threads - 1) / threads;
    lee_osc_kernel<<<blocks, threads, 0, stream>>>(x, typ, out, n);
}

// Round 7
// 2096.050 us; speedup vs baseline: 1.0036x; 1.0036x over previous
//
#include <hip/hip_runtime.h>

// Lee oscillator, 99 recurrence steps, elementwise over 4096x4096 f32.
// Chaotic 1-D map per element => must replicate XLA's float32 op sequence
// BITWISE. tanh = XLA EmitFastTanh (Eigen rational approx, with_fma=true):
//   clamp +-7.99881172180175781, Horner via true fused FMA, IEEE f32 division,
//   |x| < 0.0004 -> x passthrough.
// All other ops: single-rounded mul/add/sub in the reference's left-assoc
// order; fp contract OFF so the backend cannot fuse them.

#pragma clang fp contract(off)

#define N_ITERS 99  // N_STEPS - 1

// (a1,a2,a3,a4, b1,b2,b3,b4, xi_E, xi_I) for oscillator types 1..8
__device__ __constant__ float kCoeffs[8][10] = {
    { 0.0f,  5.0f,   5.0f,   1.0f,  0.0f, -1.0f,   1.0f,  0.0f, 0.0f, 0.0f},
    { 0.5f,  0.55f,  0.55f, -0.5f,  0.5f, -0.55f, -0.55f, -0.5f, 0.0f, 0.0f},
    {-5.0f,  5.0f,   5.0f,  -5.0f,  1.0f, -1.0f,  -1.0f,  1.0f, 0.0f, 0.0f},
    { 1.0f,  1.0f,   1.0f,  -1.0f, -1.0f, -1.0f,  -1.0f,  1.0f, 0.0f, 0.0f},
    { 5.0f, -5.0f,  -5.0f,   5.0f, -1.0f,  1.0f,   1.0f, -1.0f, 0.0f, 0.0f},
    {-1.0f, -1.0f,  -1.0f,   1.0f,  1.0f,  1.0f,   1.0f, -1.0f, 0.0f, 0.0f},
    { 1.0f, -1.0f,  -1.0f,   1.0f, -1.0f,  1.0f,   1.0f, -1.0f, 0.0f, 0.0f},
    {-1.0f,  1.0f,   1.0f,  -1.0f,  1.0f, -1.0f,  -1.0f,  1.0f, 0.0f, 0.0f},
};

// XLA EmitFastTanh / Eigen generic_fast_tanh_float, with_fma variant.
// Every op correctly rounded -> bitwise reproducible across backends.
__device__ __forceinline__ float xla_fast_tanh(float x) {
#pragma clang fp contract(off)
    const float kClamp = 7.99881172180175781f;  // with_fma clamp
    float ax = __builtin_fabsf(x);
    float xc = __builtin_fminf(__builtin_fmaxf(x, -kClamp), kClamp);
    float x2 = __fmul_rn(xc, xc);
    float p = __fmaf_rn(x2, -2.76076847742355e-16f, 2.00018790482477e-13f);
    p = __fmaf_rn(x2, p, -8.60467152213735e-11f);
    p = __fmaf_rn(x2, p, 5.12229709037114e-08f);
    p = __fmaf_rn(x2, p, 1.48572235717979e-05f);
    p = __fmaf_rn(x2, p, 6.37261928875436e-04f);
    p = __fmaf_rn(x2, p, 4.89352455891786e-03f);
    p = __fmul_rn(xc, p);
    float q = __fmaf_rn(x2, 1.19825839466702e-06f, 1.18534705686654e-04f);
    q = __fmaf_rn(x2, q, 2.26843463243900e-03f);
    q = __fmaf_rn(x2, q, 4.89352518554385e-03f);
    float r = p / q;  // IEEE-correct f32 division (default hipcc, no fast-math)
    return (ax < 0.0004f) ? x : r;
}

__global__ __launch_bounds__(256) void lee_osc_kernel(
    const float* __restrict__ x, const int* __restrict__ osc_type,
    float* __restrict__ out, int n) {
#pragma clang fp contract(off)
    int i = blockIdx.x * blockDim.x + threadIdx.x;
    if (i >= n) return;

    int t = osc_type[0];  // uniform across grid
    if (t < 1 || t > 8) t = 1;
    const float* c = kCoeffs[t - 1];
    const float a1 = c[0], a2 = c[1], a3 = c[2], a4 = c[3];
    const float b1 = c[4], b2 = c[5], b3 = c[6], b4 = c[7];
    const float xiE = c[8], xiI = c[9];

    float xv = x[i];
    // jnp.sign
    float sgn = (xv > 0.0f) ? 1.0f : ((xv < 0.0f) ? -1.0f : 0.0f);
    // sim = x + 0.001*sign(x)
    float sim = __fadd_rn(xv, __fmul_rn(0.001f, sgn));
    // gate = exp((-500*sim)*sim) — enters only linearly for type 1, ~1ulp ok
    float gq = __fmul_rn(__fmul_rn(-500.0f, sim), sim);
    float gate = expf(gq);
    // omega = tanh(5*sim) — constant, linear contribution
    float omega = xla_fast_tanh(__fmul_rn(5.0f, sim));

    float E = 0.2f, I = 0.0f, L = 0.2f;
    for (int s = 0; s < N_ITERS; ++s) {
        // E1 = tanh(5 * ((((a1*L + a2*E) - a3*I) + a4*sim) - xiE))
        float tE = __fmul_rn(a1, L);
        tE = __fadd_rn(tE, __fmul_rn(a2, E));
        tE = __fsub_rn(tE, __fmul_rn(a3, I));
        tE = __fadd_rn(tE, __fmul_rn(a4, sim));
        tE = __fsub_rn(tE, xiE);
        float E1 = xla_fast_tanh(__fmul_rn(5.0f, tE));

        // I1 = tanh(5 * ((((b1*L - b2*E) - b3*I) + b4*sim) - xiI))
        float tI = __fmul_rn(b1, L);
        tI = __fsub_rn(tI, __fmul_rn(b2, E));
        tI = __fsub_rn(tI, __fmul_rn(b3, I));
        tI = __fadd_rn(tI, __fmul_rn(b4, sim));
        tI = __fsub_rn(tI, xiI);
        float I1 = xla_fast_tanh(__fmul_rn(5.0f, tI));

        // L = (E1 - I1)*gate + omega   (mul then add, NOT fma)
        L = __fadd_rn(__fmul_rn(__fsub_rn(E1, I1), gate), omega);
        E = E1;
        I = I1;
    }
    out[i] = L;
}

extern "C" void kernel_launch(void* const* d_in, const int* in_sizes, int n_in,
                              void* d_out, int out_size, void* d_ws, size_t ws_size,
                              hipStream_t stream) {
    const float* x = (const float*)d_in[0];
    const int* typ = (const int*)d_in[1];
    float* out = (float*)d_out;
    int n = out_size;
    int threads = 256;
    int blocks = (n + threads - 1) / threads;
    lee_osc_kernel<<<blocks, threads, 0, stream>>>(x, typ, out, n);
}

// Round 8
// 303.731 us; speedup vs baseline: 6.9262x; 6.9010x over previous
//
#include <hip/hip_runtime.h>

// Lee oscillator — R7 (verified bitwise, absmax 0.0) + wave-local compaction.
// NO specialized loop body this round: survivors run the VERBATIM R7 generic
// loop with runtime kCoeffs[t-1]. Only addition: for t==1, lanes with
// gate < 1e-3 write omega (bitwise-exact; |L_ref - omega| = |E99-I99|*gate
// <= 2e-3 << 2e-2 because a1=b1=0 => L never feeds back), and survivors are
// compacted per-wave via ballot-prefix into wave-private LDS (no atomics, no
// __syncthreads, no multi-kernel, deterministic by construction).

#pragma clang fp contract(off)

#define N_ITERS 99                            // N_STEPS - 1
#define LOG_GATE_THRESH -6.9077552789821370f  // ln(1e-3)
#define BLOCK 256
#define ITERS_PER_WAVE 32
#define WSPAN (64 * ITERS_PER_WAVE)           // 2048 elements per wave
#define SPAN (4 * WSPAN)                      // 8192 elements per block
#define WL_CAP 384                            // mean 191, sigma ~13 -> +14 sigma

// (a1,a2,a3,a4, b1,b2,b3,b4, xi_E, xi_I) for oscillator types 1..8
__device__ __constant__ float kCoeffs[8][10] = {
    { 0.0f,  5.0f,   5.0f,   1.0f,  0.0f, -1.0f,   1.0f,  0.0f, 0.0f, 0.0f},
    { 0.5f,  0.55f,  0.55f, -0.5f,  0.5f, -0.55f, -0.55f, -0.5f, 0.0f, 0.0f},
    {-5.0f,  5.0f,   5.0f,  -5.0f,  1.0f, -1.0f,  -1.0f,  1.0f, 0.0f, 0.0f},
    { 1.0f,  1.0f,   1.0f,  -1.0f, -1.0f, -1.0f,  -1.0f,  1.0f, 0.0f, 0.0f},
    { 5.0f, -5.0f,  -5.0f,   5.0f, -1.0f,  1.0f,   1.0f, -1.0f, 0.0f, 0.0f},
    {-1.0f, -1.0f,  -1.0f,   1.0f,  1.0f,  1.0f,   1.0f, -1.0f, 0.0f, 0.0f},
    { 1.0f, -1.0f,  -1.0f,   1.0f, -1.0f,  1.0f,   1.0f, -1.0f, 0.0f, 0.0f},
    {-1.0f,  1.0f,   1.0f,  -1.0f,  1.0f, -1.0f,  -1.0f,  1.0f, 0.0f, 0.0f},
};

// XLA EmitFastTanh / Eigen generic_fast_tanh_float, with_fma variant.
// Every op correctly rounded -> bitwise reproducible. (R1/R7: absmax 0.0.)
__device__ __forceinline__ float xla_fast_tanh(float x) {
#pragma clang fp contract(off)
    const float kClamp = 7.99881172180175781f;
    float ax = __builtin_fabsf(x);
    float xc = __builtin_fminf(__builtin_fmaxf(x, -kClamp), kClamp);
    float x2 = __fmul_rn(xc, xc);
    float p = __fmaf_rn(x2, -2.76076847742355e-16f, 2.00018790482477e-13f);
    p = __fmaf_rn(x2, p, -8.60467152213735e-11f);
    p = __fmaf_rn(x2, p, 5.12229709037114e-08f);
    p = __fmaf_rn(x2, p, 1.48572235717979e-05f);
    p = __fmaf_rn(x2, p, 6.37261928875436e-04f);
    p = __fmaf_rn(x2, p, 4.89352455891786e-03f);
    p = __fmul_rn(xc, p);
    float q = __fmaf_rn(x2, 1.19825839466702e-06f, 1.18534705686654e-04f);
    q = __fmaf_rn(x2, q, 2.26843463243900e-03f);
    q = __fmaf_rn(x2, q, 4.89352518554385e-03f);
    float r = p / q;  // IEEE-correct f32 division
    return (ax < 0.0004f) ? x : r;
}

// VERBATIM R7 per-element computation (runtime coefficients; generic for all
// types). R1/R7 verified bitwise against the JAX reference (absmax 0.0).
__device__ __forceinline__ float lee_compute(float xv, const float* c) {
#pragma clang fp contract(off)
    const float a1 = c[0], a2 = c[1], a3 = c[2], a4 = c[3];
    const float b1 = c[4], b2 = c[5], b3 = c[6], b4 = c[7];
    const float xiE = c[8], xiI = c[9];

    float sgn = (xv > 0.0f) ? 1.0f : ((xv < 0.0f) ? -1.0f : 0.0f);
    float sim = __fadd_rn(xv, __fmul_rn(0.001f, sgn));
    float gq = __fmul_rn(__fmul_rn(-500.0f, sim), sim);
    float gate = expf(gq);
    float omega = xla_fast_tanh(__fmul_rn(5.0f, sim));

    float E = 0.2f, I = 0.0f, L = 0.2f;
    for (int s = 0; s < N_ITERS; ++s) {
        float tE = __fmul_rn(a1, L);
        tE = __fadd_rn(tE, __fmul_rn(a2, E));
        tE = __fsub_rn(tE, __fmul_rn(a3, I));
        tE = __fadd_rn(tE, __fmul_rn(a4, sim));
        tE = __fsub_rn(tE, xiE);
        float E1 = xla_fast_tanh(__fmul_rn(5.0f, tE));

        float tI = __fmul_rn(b1, L);
        tI = __fsub_rn(tI, __fmul_rn(b2, E));
        tI = __fsub_rn(tI, __fmul_rn(b3, I));
        tI = __fadd_rn(tI, __fmul_rn(b4, sim));
        tI = __fsub_rn(tI, xiI);
        float I1 = xla_fast_tanh(__fmul_rn(5.0f, tI));

        L = __fadd_rn(__fmul_rn(__fsub_rn(E1, I1), gate), omega);
        E = E1;
        I = I1;
    }
    return L;
}

__global__ __launch_bounds__(BLOCK) void lee_osc_kernel(
    const float* __restrict__ x, const int* __restrict__ osc_type,
    float* __restrict__ out, int n) {
#pragma clang fp contract(off)
    __shared__ unsigned short s_idx[4][WL_CAP];

    int t = osc_type[0];  // uniform across grid
    if (t < 1 || t > 8) t = 1;
    const float* c = kCoeffs[t - 1];

    const int wave = (int)(threadIdx.x >> 6);
    const int lane = (int)(threadIdx.x & 63);
    const int wbase = (int)blockIdx.x * SPAN + wave * WSPAN;

    if (t != 1) {
        // Non-type-1: plain R7 path for every element.
        for (int p = 0; p < ITERS_PER_WAVE; ++p) {
            int i = wbase + p * 64 + lane;
            if (i < n) out[i] = lee_compute(x[i], c);
        }
        return;
    }

    // Type 1. Phase 1: coalesced classify + ballot-prefix compaction.
    const unsigned long long lt_mask = (1ull << lane) - 1ull;  // lane<=63
    unsigned int cnt = 0;  // wave-uniform survivor count
    for (int p = 0; p < ITERS_PER_WAVE; ++p) {
        int li = p * 64 + lane;
        int i = wbase + li;
        bool valid = (i < n);
        float xv = valid ? x[i] : 1.0e9f;  // dummy classifies as skip
        float sgn = (xv > 0.0f) ? 1.0f : ((xv < 0.0f) ? -1.0f : 0.0f);
        float sim = __fadd_rn(xv, __fmul_rn(0.001f, sgn));
        float gq = __fmul_rn(__fmul_rn(-500.0f, sim), sim);
        bool surv = valid && !(gq < LOG_GATE_THRESH);
        if (valid && !surv) {
            // gate < 1e-3: |L_ref - omega| = |E99-I99|*gate <= 2e-3 << 2e-2;
            // omega here is bitwise identical to the reference's omega.
            out[i] = xla_fast_tanh(__fmul_rn(5.0f, sim));
        }
        unsigned long long mask = __ballot(surv);
        unsigned int pos = cnt + (unsigned int)__popcll(mask & lt_mask);
        if (surv) {
            if (pos < WL_CAP) s_idx[wave][pos] = (unsigned short)li;
            else out[i] = lee_compute(xv, c);  // cap overflow: exact inline
        }
        cnt += (unsigned int)__popcll(mask);
    }

    // Phase 2: dense wave-private worklist — exact loop, ~full lane occupancy.
    unsigned int m = (cnt < WL_CAP) ? cnt : WL_CAP;
    for (unsigned int j = (unsigned int)lane; j < m; j += 64u) {
        int i = wbase + (int)s_idx[wave][j];
        out[i] = lee_compute(x[i], c);
    }
}

extern "C" void kernel_launch(void* const* d_in, const int* in_sizes, int n_in,
                              void* d_out, int out_size, void* d_ws, size_t ws_size,
                              hipStream_t stream) {
    const float* x = (const float*)d_in[0];
    const int* typ = (const int*)d_in[1];
    float* out = (float*)d_out;
    int n = out_size;
    int blocks = (n + SPAN - 1) / SPAN;
    lee_osc_kernel<<<blocks, BLOCK, 0, stream>>>(x, typ, out, n);
}

// Round 10
// 294.161 us; speedup vs baseline: 7.1515x; 1.0325x over previous
//
#include <hip/hip_runtime.h>

// Lee oscillator — R8 skeleton (passed, 304 us, absmax 1 bf16-ulp) + deltas:
//  (1) WSPAN 2048 -> 4096: halves phase-2 pass-quantization waste.
//  (2) skip threshold gate<1e-3 -> gate<2e-3: err <= 4e-3 f32 (<= 2 bf16 ulp
//      = 0.0078 << 0.02 threshold); survivors -5%.
//  (3) survivor x stashed in LDS during classify; phase 2 is LDS-fed.
// NOTE: the type-1-specialized loop body is EXCLUDED deliberately — across
// R1-R9 its presence correlates 6/6 with the silent no-op failure and its
// absence 3/3 with passes. Only the generic verbatim loop appears here.

#pragma clang fp contract(off)

#define N_ITERS 99                            // N_STEPS - 1
#define LOG_GATE_THRESH -6.2146080984221916f  // ln(2e-3)
#define BLOCK 256
#define ITERS_PER_WAVE 64
#define WSPAN (64 * ITERS_PER_WAVE)           // 4096 elements per wave
#define SPAN (4 * WSPAN)                      // 16384 elements per block
#define WL_CAP 512                            // mean 360, sigma ~18 -> +8.4 sigma

// (a1,a2,a3,a4, b1,b2,b3,b4, xi_E, xi_I) for oscillator types 1..8
__device__ __constant__ float kCoeffs[8][10] = {
    { 0.0f,  5.0f,   5.0f,   1.0f,  0.0f, -1.0f,   1.0f,  0.0f, 0.0f, 0.0f},
    { 0.5f,  0.55f,  0.55f, -0.5f,  0.5f, -0.55f, -0.55f, -0.5f, 0.0f, 0.0f},
    {-5.0f,  5.0f,   5.0f,  -5.0f,  1.0f, -1.0f,  -1.0f,  1.0f, 0.0f, 0.0f},
    { 1.0f,  1.0f,   1.0f,  -1.0f, -1.0f, -1.0f,  -1.0f,  1.0f, 0.0f, 0.0f},
    { 5.0f, -5.0f,  -5.0f,   5.0f, -1.0f,  1.0f,   1.0f, -1.0f, 0.0f, 0.0f},
    {-1.0f, -1.0f,  -1.0f,   1.0f,  1.0f,  1.0f,   1.0f, -1.0f, 0.0f, 0.0f},
    { 1.0f, -1.0f,  -1.0f,   1.0f, -1.0f,  1.0f,   1.0f, -1.0f, 0.0f, 0.0f},
    {-1.0f,  1.0f,   1.0f,  -1.0f,  1.0f, -1.0f,  -1.0f,  1.0f, 0.0f, 0.0f},
};

// XLA EmitFastTanh / Eigen generic_fast_tanh_float, with_fma variant.
// Every op correctly rounded -> bitwise reproducible. (R1/R7/R8: exact.)
__device__ __forceinline__ float xla_fast_tanh(float x) {
#pragma clang fp contract(off)
    const float kClamp = 7.99881172180175781f;
    float ax = __builtin_fabsf(x);
    float xc = __builtin_fminf(__builtin_fmaxf(x, -kClamp), kClamp);
    float x2 = __fmul_rn(xc, xc);
    float p = __fmaf_rn(x2, -2.76076847742355e-16f, 2.00018790482477e-13f);
    p = __fmaf_rn(x2, p, -8.60467152213735e-11f);
    p = __fmaf_rn(x2, p, 5.12229709037114e-08f);
    p = __fmaf_rn(x2, p, 1.48572235717979e-05f);
    p = __fmaf_rn(x2, p, 6.37261928875436e-04f);
    p = __fmaf_rn(x2, p, 4.89352455891786e-03f);
    p = __fmul_rn(xc, p);
    float q = __fmaf_rn(x2, 1.19825839466702e-06f, 1.18534705686654e-04f);
    q = __fmaf_rn(x2, q, 2.26843463243900e-03f);
    q = __fmaf_rn(x2, q, 4.89352518554385e-03f);
    float r = p / q;  // IEEE-correct f32 division
    return (ax < 0.0004f) ? x : r;
}

// Generic exact trajectory (ALL types) — verbatim R1/R7 (verified bitwise,
// absmax 0.0). This is the only trajectory loop in this file.
__device__ __forceinline__ float lee_compute(float xv, const float* c) {
#pragma clang fp contract(off)
    const float a1 = c[0], a2 = c[1], a3 = c[2], a4 = c[3];
    const float b1 = c[4], b2 = c[5], b3 = c[6], b4 = c[7];
    const float xiE = c[8], xiI = c[9];

    float sgn = (xv > 0.0f) ? 1.0f : ((xv < 0.0f) ? -1.0f : 0.0f);
    float sim = __fadd_rn(xv, __fmul_rn(0.001f, sgn));
    float gq = __fmul_rn(__fmul_rn(-500.0f, sim), sim);
    float gate = expf(gq);
    float omega = xla_fast_tanh(__fmul_rn(5.0f, sim));

    float E = 0.2f, I = 0.0f, L = 0.2f;
    for (int s = 0; s < N_ITERS; ++s) {
        float tE = __fmul_rn(a1, L);
        tE = __fadd_rn(tE, __fmul_rn(a2, E));
        tE = __fsub_rn(tE, __fmul_rn(a3, I));
        tE = __fadd_rn(tE, __fmul_rn(a4, sim));
        tE = __fsub_rn(tE, xiE);
        float E1 = xla_fast_tanh(__fmul_rn(5.0f, tE));

        float tI = __fmul_rn(b1, L);
        tI = __fsub_rn(tI, __fmul_rn(b2, E));
        tI = __fsub_rn(tI, __fmul_rn(b3, I));
        tI = __fadd_rn(tI, __fmul_rn(b4, sim));
        tI = __fsub_rn(tI, xiI);
        float I1 = xla_fast_tanh(__fmul_rn(5.0f, tI));

        L = __fadd_rn(__fmul_rn(__fsub_rn(E1, I1), gate), omega);
        E = E1;
        I = I1;
    }
    return L;
}

__global__ __launch_bounds__(BLOCK) void lee_osc_kernel(
    const float* __restrict__ x, const int* __restrict__ osc_type,
    float* __restrict__ out, int n) {
#pragma clang fp contract(off)
    __shared__ unsigned short s_idx[4][WL_CAP];
    __shared__ float s_x[4][WL_CAP];

    int t = osc_type[0];  // uniform across grid
    if (t < 1 || t > 8) t = 1;
    const float* c = kCoeffs[t - 1];

    const int wave = (int)(threadIdx.x >> 6);
    const int lane = (int)(threadIdx.x & 63);
    const int wbase = (int)blockIdx.x * SPAN + wave * WSPAN;

    if (t != 1) {
        // Non-type-1: plain exact path for every element.
        for (int p = 0; p < ITERS_PER_WAVE; ++p) {
            int i = wbase + p * 64 + lane;
            if (i < n) out[i] = lee_compute(x[i], c);
        }
        return;
    }

    // Type 1. Phase 1: coalesced classify + ballot-prefix compaction.
    // Skip rule: gate < 2e-3 => |L_ref - omega| = |E99-I99|*gate < 4e-3
    // (a1=b1=0 so L never feeds back); omega written bitwise-exact.
    const unsigned long long lt_mask = (1ull << lane) - 1ull;  // lane<=63
    unsigned int cnt = 0;  // wave-uniform survivor count
    for (int p = 0; p < ITERS_PER_WAVE; ++p) {
        int li = p * 64 + lane;
        int i = wbase + li;
        bool valid = (i < n);
        float xv = valid ? x[i] : 1.0e9f;  // dummy classifies as skip
        float sgn = (xv > 0.0f) ? 1.0f : ((xv < 0.0f) ? -1.0f : 0.0f);
        float sim = __fadd_rn(xv, __fmul_rn(0.001f, sgn));
        float gq = __fmul_rn(__fmul_rn(-500.0f, sim), sim);
        bool surv = valid && !(gq < LOG_GATE_THRESH);
        if (valid && !surv) {
            out[i] = xla_fast_tanh(__fmul_rn(5.0f, sim));  // omega, exact
        }
        unsigned long long mask = __ballot(surv);
        unsigned int pos = cnt + (unsigned int)__popcll(mask & lt_mask);
        if (surv) {
            if (pos < WL_CAP) {
                s_idx[wave][pos] = (unsigned short)li;
                s_x[wave][pos] = xv;
            } else {
                out[i] = lee_compute(xv, c);  // cap overflow: exact inline
            }
        }
        cnt += (unsigned int)__popcll(mask);
    }

    // Phase 2: dense wave-private worklist — exact generic loop, LDS-fed.
    unsigned int m = (cnt < WL_CAP) ? cnt : WL_CAP;
    for (unsigned int j = (unsigned int)lane; j < m; j += 64u) {
        int i = wbase + (int)s_idx[wave][j];
        float xv = s_x[wave][j];
        out[i] = lee_compute(xv, c);
    }
}

extern "C" void kernel_launch(void* const* d_in, const int* in_sizes, int n_in,
                              void* d_out, int out_size, void* d_ws, size_t ws_size,
                              hipStream_t stream) {
    const float* x = (const float*)d_in[0];
    const int* typ = (const int*)d_in[1];
    float* out = (float*)d_out;
    int n = out_size;
    int blocks = (n + SPAN - 1) / SPAN;
    lee_osc_kernel<<<blocks, BLOCK, 0, stream>>>(x, typ, out, n);
}

// Round 11
// 255.172 us; speedup vs baseline: 8.2442x; 1.1528x over previous
//
#include <hip/hip_runtime.h>

// Lee oscillator — global two-level compaction, poison-free.
//  Kernel A: R10's proven per-wave ballot-prefix classify (skip lanes write
//    bitwise-exact omega), wave-private LDS stash, then ONE global atomicAdd
//    per block reserves a contiguous worklist slab in d_ws (SoA idx+x),
//    flushed coalesced. Overflow -> exact inline compute.
//  Kernel B: grid-stride over the dense worklist at full occupancy — removes
//    R10's per-wave pass-quantization (~7%) and its 31%-occupancy ceiling.
// The ONLY trajectory code is the generic verbatim loop (bitwise-verified
// R1/R7; the type-1-specialized body correlates 6/6 with silent no-op
// failures and is permanently excluded). Skip rule: t==1 & gate<2e-3 ->
// |L_ref-omega| <= 4e-3 (a1=b1=0 => L never feeds back); measured 1 bf16 ulp.

#pragma clang fp contract(off)

#define N_ITERS 99                            // N_STEPS - 1
#define LOG_GATE_THRESH -6.2146080984221916f  // ln(2e-3)
#define BLOCK 256
#define ITERS_PER_WAVE 64
#define WSPAN (64 * ITERS_PER_WAVE)           // 4096 elements per wave
#define SPAN (4 * WSPAN)                      // 16384 elements per block
#define WL_CAP 512                            // per-wave LDS cap (mean 360, +8 sigma)

// (a1,a2,a3,a4, b1,b2,b3,b4, xi_E, xi_I) for oscillator types 1..8
__device__ __constant__ float kCoeffs[8][10] = {
    { 0.0f,  5.0f,   5.0f,   1.0f,  0.0f, -1.0f,   1.0f,  0.0f, 0.0f, 0.0f},
    { 0.5f,  0.55f,  0.55f, -0.5f,  0.5f, -0.55f, -0.55f, -0.5f, 0.0f, 0.0f},
    {-5.0f,  5.0f,   5.0f,  -5.0f,  1.0f, -1.0f,  -1.0f,  1.0f, 0.0f, 0.0f},
    { 1.0f,  1.0f,   1.0f,  -1.0f, -1.0f, -1.0f,  -1.0f,  1.0f, 0.0f, 0.0f},
    { 5.0f, -5.0f,  -5.0f,   5.0f, -1.0f,  1.0f,   1.0f, -1.0f, 0.0f, 0.0f},
    {-1.0f, -1.0f,  -1.0f,   1.0f,  1.0f,  1.0f,   1.0f, -1.0f, 0.0f, 0.0f},
    { 1.0f, -1.0f,  -1.0f,   1.0f, -1.0f,  1.0f,   1.0f, -1.0f, 0.0f, 0.0f},
    {-1.0f,  1.0f,   1.0f,  -1.0f,  1.0f, -1.0f,  -1.0f,  1.0f, 0.0f, 0.0f},
};

// XLA EmitFastTanh / Eigen generic_fast_tanh_float, with_fma variant.
// Every op correctly rounded -> bitwise reproducible. (R1/R7/R8/R10: exact.)
__device__ __forceinline__ float xla_fast_tanh(float x) {
#pragma clang fp contract(off)
    const float kClamp = 7.99881172180175781f;
    float ax = __builtin_fabsf(x);
    float xc = __builtin_fminf(__builtin_fmaxf(x, -kClamp), kClamp);
    float x2 = __fmul_rn(xc, xc);
    float p = __fmaf_rn(x2, -2.76076847742355e-16f, 2.00018790482477e-13f);
    p = __fmaf_rn(x2, p, -8.60467152213735e-11f);
    p = __fmaf_rn(x2, p, 5.12229709037114e-08f);
    p = __fmaf_rn(x2, p, 1.48572235717979e-05f);
    p = __fmaf_rn(x2, p, 6.37261928875436e-04f);
    p = __fmaf_rn(x2, p, 4.89352455891786e-03f);
    p = __fmul_rn(xc, p);
    float q = __fmaf_rn(x2, 1.19825839466702e-06f, 1.18534705686654e-04f);
    q = __fmaf_rn(x2, q, 2.26843463243900e-03f);
    q = __fmaf_rn(x2, q, 4.89352518554385e-03f);
    float r = p / q;  // IEEE-correct f32 division
    return (ax < 0.0004f) ? x : r;
}

// Generic exact trajectory (ALL types) — verbatim R1/R7 (verified bitwise).
__device__ __forceinline__ float lee_compute(float xv, const float* c) {
#pragma clang fp contract(off)
    const float a1 = c[0], a2 = c[1], a3 = c[2], a4 = c[3];
    const float b1 = c[4], b2 = c[5], b3 = c[6], b4 = c[7];
    const float xiE = c[8], xiI = c[9];

    float sgn = (xv > 0.0f) ? 1.0f : ((xv < 0.0f) ? -1.0f : 0.0f);
    float sim = __fadd_rn(xv, __fmul_rn(0.001f, sgn));
    float gq = __fmul_rn(__fmul_rn(-500.0f, sim), sim);
    float gate = expf(gq);
    float omega = xla_fast_tanh(__fmul_rn(5.0f, sim));

    float E = 0.2f, I = 0.0f, L = 0.2f;
    for (int s = 0; s < N_ITERS; ++s) {
        float tE = __fmul_rn(a1, L);
        tE = __fadd_rn(tE, __fmul_rn(a2, E));
        tE = __fsub_rn(tE, __fmul_rn(a3, I));
        tE = __fadd_rn(tE, __fmul_rn(a4, sim));
        tE = __fsub_rn(tE, xiE);
        float E1 = xla_fast_tanh(__fmul_rn(5.0f, tE));

        float tI = __fmul_rn(b1, L);
        tI = __fsub_rn(tI, __fmul_rn(b2, E));
        tI = __fsub_rn(tI, __fmul_rn(b3, I));
        tI = __fadd_rn(tI, __fmul_rn(b4, sim));
        tI = __fsub_rn(tI, xiI);
        float I1 = xla_fast_tanh(__fmul_rn(5.0f, tI));

        L = __fadd_rn(__fmul_rn(__fsub_rn(E1, I1), gate), omega);
        E = E1;
        I = I1;
    }
    return L;
}

__global__ void lee_zero_counter(unsigned int* __restrict__ count) {
    if (threadIdx.x == 0 && blockIdx.x == 0) count[0] = 0u;
}

// Kernel A: classify + wave-local LDS compaction + one global reservation
// per block + coalesced flush to the global worklist.
__global__ __launch_bounds__(BLOCK) void lee_classify(
    const float* __restrict__ x, const int* __restrict__ osc_type,
    float* __restrict__ out, unsigned int* __restrict__ count,
    unsigned int* __restrict__ wl_idx, float* __restrict__ wl_x,
    unsigned int cap, int n) {
#pragma clang fp contract(off)
    __shared__ unsigned short s_idx[4][WL_CAP];
    __shared__ float s_x[4][WL_CAP];
    __shared__ unsigned int s_cnt[4];
    __shared__ unsigned int s_base;
    __shared__ unsigned int s_off[4];

    int t = osc_type[0];
    if (t < 1 || t > 8) t = 1;
    const float* c = kCoeffs[t - 1];

    const int wave = (int)(threadIdx.x >> 6);
    const int lane = (int)(threadIdx.x & 63);
    const int wbase = (int)blockIdx.x * SPAN + wave * WSPAN;

    if (t != 1) {
        // Non-type-1: plain exact path for every element; count stays 0.
        for (int p = 0; p < ITERS_PER_WAVE; ++p) {
            int i = wbase + p * 64 + lane;
            if (i < n) out[i] = lee_compute(x[i], c);
        }
        return;
    }

    // Phase 1: coalesced classify + ballot-prefix compaction (R10-proven).
    const unsigned long long lt_mask = (1ull << lane) - 1ull;  // lane<=63
    unsigned int cnt = 0;  // wave-uniform survivor count
    for (int p = 0; p < ITERS_PER_WAVE; ++p) {
        int li = p * 64 + lane;
        int i = wbase + li;
        bool valid = (i < n);
        float xv = valid ? x[i] : 1.0e9f;  // dummy classifies as skip
        float sgn = (xv > 0.0f) ? 1.0f : ((xv < 0.0f) ? -1.0f : 0.0f);
        float sim = __fadd_rn(xv, __fmul_rn(0.001f, sgn));
        float gq = __fmul_rn(__fmul_rn(-500.0f, sim), sim);
        bool surv = valid && !(gq < LOG_GATE_THRESH);
        if (valid && !surv) {
            out[i] = xla_fast_tanh(__fmul_rn(5.0f, sim));  // omega, exact
        }
        unsigned long long mask = __ballot(surv);
        unsigned int pos = cnt + (unsigned int)__popcll(mask & lt_mask);
        if (surv) {
            if (pos < WL_CAP) {
                s_idx[wave][pos] = (unsigned short)li;
                s_x[wave][pos] = xv;
            } else {
                out[i] = lee_compute(xv, c);  // LDS-cap overflow: exact inline
            }
        }
        cnt += (unsigned int)__popcll(mask);
    }
    if (lane == 0) s_cnt[wave] = (cnt < WL_CAP) ? cnt : WL_CAP;
    __syncthreads();

    // One global reservation per block.
    if (threadIdx.x == 0) {
        unsigned int o0 = 0;
        unsigned int offs[4];
        for (int w = 0; w < 4; ++w) { offs[w] = o0; o0 += s_cnt[w]; }
        s_base = atomicAdd(count, o0);
        for (int w = 0; w < 4; ++w) s_off[w] = offs[w];
    }
    __syncthreads();

    // Coalesced flush of this wave's survivors to the global worklist.
    unsigned int wcnt = s_cnt[wave];
    unsigned int gb = s_base + s_off[wave];
    for (unsigned int j = (unsigned int)lane; j < wcnt; j += 64u) {
        unsigned int g = gb + j;
        int i = wbase + (int)s_idx[wave][j];
        float xv = s_x[wave][j];
        if (g < cap) {
            wl_idx[g] = (unsigned int)i;
            wl_x[g] = xv;
        } else {
            out[i] = lee_compute(xv, c);  // global-cap overflow: exact inline
        }
    }
}

// Kernel B: dense worklist, grid-stride, full occupancy, perfect packing.
__global__ __launch_bounds__(BLOCK) void lee_worklist(
    const int* __restrict__ osc_type, float* __restrict__ out,
    const unsigned int* __restrict__ count,
    const unsigned int* __restrict__ wl_idx, const float* __restrict__ wl_x,
    unsigned int cap, int n) {
#pragma clang fp contract(off)
    unsigned int m = count[0];
    if (m > cap) m = cap;
    int t = osc_type[0];
    if (t < 1 || t > 8) t = 1;
    const float* c = kCoeffs[t - 1];
    unsigned int stride = gridDim.x * BLOCK;
    for (unsigned int j = blockIdx.x * BLOCK + threadIdx.x; j < m; j += stride) {
        unsigned int i = wl_idx[j];
        float xv = wl_x[j];
        if (i < (unsigned int)n) out[i] = lee_compute(xv, c);
    }
}

// Fallback: R10's verified single-kernel (used only if d_ws is too small).
__global__ __launch_bounds__(BLOCK) void lee_osc_fallback(
    const float* __restrict__ x, const int* __restrict__ osc_type,
    float* __restrict__ out, int n) {
#pragma clang fp contract(off)
    __shared__ unsigned short s_idx[4][WL_CAP];
    __shared__ float s_x[4][WL_CAP];

    int t = osc_type[0];
    if (t < 1 || t > 8) t = 1;
    const float* c = kCoeffs[t - 1];

    const int wave = (int)(threadIdx.x >> 6);
    const int lane = (int)(threadIdx.x & 63);
    const int wbase = (int)blockIdx.x * SPAN + wave * WSPAN;

    if (t != 1) {
        for (int p = 0; p < ITERS_PER_WAVE; ++p) {
            int i = wbase + p * 64 + lane;
            if (i < n) out[i] = lee_compute(x[i], c);
        }
        return;
    }

    const unsigned long long lt_mask = (1ull << lane) - 1ull;
    unsigned int cnt = 0;
    for (int p = 0; p < ITERS_PER_WAVE; ++p) {
        int li = p * 64 + lane;
        int i = wbase + li;
        bool valid = (i < n);
        float xv = valid ? x[i] : 1.0e9f;
        float sgn = (xv > 0.0f) ? 1.0f : ((xv < 0.0f) ? -1.0f : 0.0f);
        float sim = __fadd_rn(xv, __fmul_rn(0.001f, sgn));
        float gq = __fmul_rn(__fmul_rn(-500.0f, sim), sim);
        bool surv = valid && !(gq < LOG_GATE_THRESH);
        if (valid && !surv) out[i] = xla_fast_tanh(__fmul_rn(5.0f, sim));
        unsigned long long mask = __ballot(surv);
        unsigned int pos = cnt + (unsigned int)__popcll(mask & lt_mask);
        if (surv) {
            if (pos < WL_CAP) { s_idx[wave][pos] = (unsigned short)li; s_x[wave][pos] = xv; }
            else out[i] = lee_compute(xv, c);
        }
        cnt += (unsigned int)__popcll(mask);
    }
    unsigned int m = (cnt < WL_CAP) ? cnt : WL_CAP;
    for (unsigned int j = (unsigned int)lane; j < m; j += 64u) {
        int i = wbase + (int)s_idx[wave][j];
        out[i] = lee_compute(s_x[wave][j], c);
    }
}

extern "C" void kernel_launch(void* const* d_in, const int* in_sizes, int n_in,
                              void* d_out, int out_size, void* d_ws, size_t ws_size,
                              hipStream_t stream) {
    const float* x = (const float*)d_in[0];
    const int* typ = (const int*)d_in[1];
    float* out = (float*)d_out;
    int n = out_size;
    int blocksA = (n + SPAN - 1) / SPAN;

    // Worklist layout in d_ws: [0,16) counter; [16,16+4*cap) idx; then x.
    unsigned int cap = (ws_size > 16) ? (unsigned int)((ws_size - 16) / 8) : 0u;
    unsigned int need = (unsigned int)(n / 8) + 1024u;  // survivors ~8.8% whp

    if (cap < need) {
        lee_osc_fallback<<<blocksA, BLOCK, 0, stream>>>(x, typ, out, n);
        return;
    }

    unsigned int* count = (unsigned int*)d_ws;
    unsigned int* wl_idx = (unsigned int*)((char*)d_ws + 16);
    float* wl_x = (float*)((char*)d_ws + 16 + (size_t)cap * 4u);

    lee_zero_counter<<<1, 64, 0, stream>>>(count);
    lee_classify<<<blocksA, BLOCK, 0, stream>>>(x, typ, out, count, wl_idx, wl_x, cap, n);
    lee_worklist<<<2048, BLOCK, 0, stream>>>(typ, out, count, wl_idx, wl_x, cap, n);
}

// Round 12
// 251.186 us; speedup vs baseline: 8.3750x; 1.0159x over previous
//
#include <hip/hip_runtime.h>

// Lee oscillator — R11 (passed, 255 us) with ONE delta: kernel B launched
// with 8192 blocks so each thread handles <= 1 worklist entry (perfect
// balance; R11's 2048-block grid-stride made 80% of threads run 3 entries
// and 20% run 2, idling waves in the tail at 56% occupancy).
//  Kernel A: per-wave ballot-prefix classify (skip lanes write bitwise-exact
//    omega), wave-private LDS stash, ONE global atomicAdd per block reserves
//    a contiguous worklist slab in d_ws (SoA idx+x), coalesced flush.
//  Kernel B: dense worklist, 1 entry/thread, full occupancy.
// The ONLY trajectory code is the generic verbatim loop (bitwise-verified
// R1/R7; the type-1-specialized body correlates 6/6 with silent no-op
// failures and is permanently excluded). Skip rule: t==1 & gate<2e-3 ->
// |L_ref-omega| <= 4e-3 (a1=b1=0 => L never feeds back); measured 1 bf16 ulp.

#pragma clang fp contract(off)

#define N_ITERS 99                            // N_STEPS - 1
#define LOG_GATE_THRESH -6.2146080984221916f  // ln(2e-3)
#define BLOCK 256
#define ITERS_PER_WAVE 64
#define WSPAN (64 * ITERS_PER_WAVE)           // 4096 elements per wave
#define SPAN (4 * WSPAN)                      // 16384 elements per block
#define WL_CAP 512                            // per-wave LDS cap (mean 360, +8 sigma)

// (a1,a2,a3,a4, b1,b2,b3,b4, xi_E, xi_I) for oscillator types 1..8
__device__ __constant__ float kCoeffs[8][10] = {
    { 0.0f,  5.0f,   5.0f,   1.0f,  0.0f, -1.0f,   1.0f,  0.0f, 0.0f, 0.0f},
    { 0.5f,  0.55f,  0.55f, -0.5f,  0.5f, -0.55f, -0.55f, -0.5f, 0.0f, 0.0f},
    {-5.0f,  5.0f,   5.0f,  -5.0f,  1.0f, -1.0f,  -1.0f,  1.0f, 0.0f, 0.0f},
    { 1.0f,  1.0f,   1.0f,  -1.0f, -1.0f, -1.0f,  -1.0f,  1.0f, 0.0f, 0.0f},
    { 5.0f, -5.0f,  -5.0f,   5.0f, -1.0f,  1.0f,   1.0f, -1.0f, 0.0f, 0.0f},
    {-1.0f, -1.0f,  -1.0f,   1.0f,  1.0f,  1.0f,   1.0f, -1.0f, 0.0f, 0.0f},
    { 1.0f, -1.0f,  -1.0f,   1.0f, -1.0f,  1.0f,   1.0f, -1.0f, 0.0f, 0.0f},
    {-1.0f,  1.0f,   1.0f,  -1.0f,  1.0f, -1.0f,  -1.0f,  1.0f, 0.0f, 0.0f},
};

// XLA EmitFastTanh / Eigen generic_fast_tanh_float, with_fma variant.
// Every op correctly rounded -> bitwise reproducible. (R1/R7/R8/R10/R11.)
__device__ __forceinline__ float xla_fast_tanh(float x) {
#pragma clang fp contract(off)
    const float kClamp = 7.99881172180175781f;
    float ax = __builtin_fabsf(x);
    float xc = __builtin_fminf(__builtin_fmaxf(x, -kClamp), kClamp);
    float x2 = __fmul_rn(xc, xc);
    float p = __fmaf_rn(x2, -2.76076847742355e-16f, 2.00018790482477e-13f);
    p = __fmaf_rn(x2, p, -8.60467152213735e-11f);
    p = __fmaf_rn(x2, p, 5.12229709037114e-08f);
    p = __fmaf_rn(x2, p, 1.48572235717979e-05f);
    p = __fmaf_rn(x2, p, 6.37261928875436e-04f);
    p = __fmaf_rn(x2, p, 4.89352455891786e-03f);
    p = __fmul_rn(xc, p);
    float q = __fmaf_rn(x2, 1.19825839466702e-06f, 1.18534705686654e-04f);
    q = __fmaf_rn(x2, q, 2.26843463243900e-03f);
    q = __fmaf_rn(x2, q, 4.89352518554385e-03f);
    float r = p / q;  // IEEE-correct f32 division
    return (ax < 0.0004f) ? x : r;
}

// Generic exact trajectory (ALL types) — verbatim R1/R7 (verified bitwise).
__device__ __forceinline__ float lee_compute(float xv, const float* c) {
#pragma clang fp contract(off)
    const float a1 = c[0], a2 = c[1], a3 = c[2], a4 = c[3];
    const float b1 = c[4], b2 = c[5], b3 = c[6], b4 = c[7];
    const float xiE = c[8], xiI = c[9];

    float sgn = (xv > 0.0f) ? 1.0f : ((xv < 0.0f) ? -1.0f : 0.0f);
    float sim = __fadd_rn(xv, __fmul_rn(0.001f, sgn));
    float gq = __fmul_rn(__fmul_rn(-500.0f, sim), sim);
    float gate = expf(gq);
    float omega = xla_fast_tanh(__fmul_rn(5.0f, sim));

    float E = 0.2f, I = 0.0f, L = 0.2f;
    for (int s = 0; s < N_ITERS; ++s) {
        float tE = __fmul_rn(a1, L);
        tE = __fadd_rn(tE, __fmul_rn(a2, E));
        tE = __fsub_rn(tE, __fmul_rn(a3, I));
        tE = __fadd_rn(tE, __fmul_rn(a4, sim));
        tE = __fsub_rn(tE, xiE);
        float E1 = xla_fast_tanh(__fmul_rn(5.0f, tE));

        float tI = __fmul_rn(b1, L);
        tI = __fsub_rn(tI, __fmul_rn(b2, E));
        tI = __fsub_rn(tI, __fmul_rn(b3, I));
        tI = __fadd_rn(tI, __fmul_rn(b4, sim));
        tI = __fsub_rn(tI, xiI);
        float I1 = xla_fast_tanh(__fmul_rn(5.0f, tI));

        L = __fadd_rn(__fmul_rn(__fsub_rn(E1, I1), gate), omega);
        E = E1;
        I = I1;
    }
    return L;
}

__global__ void lee_zero_counter(unsigned int* __restrict__ count) {
    if (threadIdx.x == 0 && blockIdx.x == 0) count[0] = 0u;
}

// Kernel A: classify + wave-local LDS compaction + one global reservation
// per block + coalesced flush to the global worklist.
__global__ __launch_bounds__(BLOCK) void lee_classify(
    const float* __restrict__ x, const int* __restrict__ osc_type,
    float* __restrict__ out, unsigned int* __restrict__ count,
    unsigned int* __restrict__ wl_idx, float* __restrict__ wl_x,
    unsigned int cap, int n) {
#pragma clang fp contract(off)
    __shared__ unsigned short s_idx[4][WL_CAP];
    __shared__ float s_x[4][WL_CAP];
    __shared__ unsigned int s_cnt[4];
    __shared__ unsigned int s_base;
    __shared__ unsigned int s_off[4];

    int t = osc_type[0];
    if (t < 1 || t > 8) t = 1;
    const float* c = kCoeffs[t - 1];

    const int wave = (int)(threadIdx.x >> 6);
    const int lane = (int)(threadIdx.x & 63);
    const int wbase = (int)blockIdx.x * SPAN + wave * WSPAN;

    if (t != 1) {
        // Non-type-1: plain exact path for every element; count stays 0.
        for (int p = 0; p < ITERS_PER_WAVE; ++p) {
            int i = wbase + p * 64 + lane;
            if (i < n) out[i] = lee_compute(x[i], c);
        }
        return;
    }

    // Phase 1: coalesced classify + ballot-prefix compaction (R10-proven).
    const unsigned long long lt_mask = (1ull << lane) - 1ull;  // lane<=63
    unsigned int cnt = 0;  // wave-uniform survivor count
    for (int p = 0; p < ITERS_PER_WAVE; ++p) {
        int li = p * 64 + lane;
        int i = wbase + li;
        bool valid = (i < n);
        float xv = valid ? x[i] : 1.0e9f;  // dummy classifies as skip
        float sgn = (xv > 0.0f) ? 1.0f : ((xv < 0.0f) ? -1.0f : 0.0f);
        float sim = __fadd_rn(xv, __fmul_rn(0.001f, sgn));
        float gq = __fmul_rn(__fmul_rn(-500.0f, sim), sim);
        bool surv = valid && !(gq < LOG_GATE_THRESH);
        if (valid && !surv) {
            out[i] = xla_fast_tanh(__fmul_rn(5.0f, sim));  // omega, exact
        }
        unsigned long long mask = __ballot(surv);
        unsigned int pos = cnt + (unsigned int)__popcll(mask & lt_mask);
        if (surv) {
            if (pos < WL_CAP) {
                s_idx[wave][pos] = (unsigned short)li;
                s_x[wave][pos] = xv;
            } else {
                out[i] = lee_compute(xv, c);  // LDS-cap overflow: exact inline
            }
        }
        cnt += (unsigned int)__popcll(mask);
    }
    if (lane == 0) s_cnt[wave] = (cnt < WL_CAP) ? cnt : WL_CAP;
    __syncthreads();

    // One global reservation per block.
    if (threadIdx.x == 0) {
        unsigned int o0 = 0;
        unsigned int offs[4];
        for (int w = 0; w < 4; ++w) { offs[w] = o0; o0 += s_cnt[w]; }
        s_base = atomicAdd(count, o0);
        for (int w = 0; w < 4; ++w) s_off[w] = offs[w];
    }
    __syncthreads();

    // Coalesced flush of this wave's survivors to the global worklist.
    unsigned int wcnt = s_cnt[wave];
    unsigned int gb = s_base + s_off[wave];
    for (unsigned int j = (unsigned int)lane; j < wcnt; j += 64u) {
        unsigned int g = gb + j;
        int i = wbase + (int)s_idx[wave][j];
        float xv = s_x[wave][j];
        if (g < cap) {
            wl_idx[g] = (unsigned int)i;
            wl_x[g] = xv;
        } else {
            out[i] = lee_compute(xv, c);  // global-cap overflow: exact inline
        }
    }
}

// Kernel B: dense worklist, <=1 entry per thread (8192 blocks = 2.1M threads
// >= m ~ 1.47M), perfectly balanced; grid-stride loop kept as armor only.
__global__ __launch_bounds__(BLOCK) void lee_worklist(
    const int* __restrict__ osc_type, float* __restrict__ out,
    const unsigned int* __restrict__ count,
    const unsigned int* __restrict__ wl_idx, const float* __restrict__ wl_x,
    unsigned int cap, int n) {
#pragma clang fp contract(off)
    unsigned int m = count[0];
    if (m > cap) m = cap;
    int t = osc_type[0];
    if (t < 1 || t > 8) t = 1;
    const float* c = kCoeffs[t - 1];
    unsigned int stride = gridDim.x * BLOCK;
    for (unsigned int j = blockIdx.x * BLOCK + threadIdx.x; j < m; j += stride) {
        unsigned int i = wl_idx[j];
        float xv = wl_x[j];
        if (i < (unsigned int)n) out[i] = lee_compute(xv, c);
    }
}

// Fallback: R10's verified single-kernel (used only if d_ws is too small).
__global__ __launch_bounds__(BLOCK) void lee_osc_fallback(
    const float* __restrict__ x, const int* __restrict__ osc_type,
    float* __restrict__ out, int n) {
#pragma clang fp contract(off)
    __shared__ unsigned short s_idx[4][WL_CAP];
    __shared__ float s_x[4][WL_CAP];

    int t = osc_type[0];
    if (t < 1 || t > 8) t = 1;
    const float* c = kCoeffs[t - 1];

    const int wave = (int)(threadIdx.x >> 6);
    const int lane = (int)(threadIdx.x & 63);
    const int wbase = (int)blockIdx.x * SPAN + wave * WSPAN;

    if (t != 1) {
        for (int p = 0; p < ITERS_PER_WAVE; ++p) {
            int i = wbase + p * 64 + lane;
            if (i < n) out[i] = lee_compute(x[i], c);
        }
        return;
    }

    const unsigned long long lt_mask = (1ull << lane) - 1ull;
    unsigned int cnt = 0;
    for (int p = 0; p < ITERS_PER_WAVE; ++p) {
        int li = p * 64 + lane;
        int i = wbase + li;
        bool valid = (i < n);
        float xv = valid ? x[i] : 1.0e9f;
        float sgn = (xv > 0.0f) ? 1.0f : ((xv < 0.0f) ? -1.0f : 0.0f);
        float sim = __fadd_rn(xv, __fmul_rn(0.001f, sgn));
        float gq = __fmul_rn(__fmul_rn(-500.0f, sim), sim);
        bool surv = valid && !(gq < LOG_GATE_THRESH);
        if (valid && !surv) out[i] = xla_fast_tanh(__fmul_rn(5.0f, sim));
        unsigned long long mask = __ballot(surv);
        unsigned int pos = cnt + (unsigned int)__popcll(mask & lt_mask);
        if (surv) {
            if (pos < WL_CAP) { s_idx[wave][pos] = (unsigned short)li; s_x[wave][pos] = xv; }
            else out[i] = lee_compute(xv, c);
        }
        cnt += (unsigned int)__popcll(mask);
    }
    unsigned int m = (cnt < WL_CAP) ? cnt : WL_CAP;
    for (unsigned int j = (unsigned int)lane; j < m; j += 64u) {
        int i = wbase + (int)s_idx[wave][j];
        out[i] = lee_compute(s_x[wave][j], c);
    }
}

extern "C" void kernel_launch(void* const* d_in, const int* in_sizes, int n_in,
                              void* d_out, int out_size, void* d_ws, size_t ws_size,
                              hipStream_t stream) {
    const float* x = (const float*)d_in[0];
    const int* typ = (const int*)d_in[1];
    float* out = (float*)d_out;
    int n = out_size;
    int blocksA = (n + SPAN - 1) / SPAN;

    // Worklist layout in d_ws: [0,16) counter; [16,16+4*cap) idx; then x.
    unsigned int cap = (ws_size > 16) ? (unsigned int)((ws_size - 16) / 8) : 0u;
    unsigned int need = (unsigned int)(n / 8) + 1024u;  // survivors ~8.8% whp

    if (cap < need) {
        lee_osc_fallback<<<blocksA, BLOCK, 0, stream>>>(x, typ, out, n);
        return;
    }

    unsigned int* count = (unsigned int*)d_ws;
    unsigned int* wl_idx = (unsigned int*)((char*)d_ws + 16);
    float* wl_x = (float*)((char*)d_ws + 16 + (size_t)cap * 4u);

    lee_zero_counter<<<1, 64, 0, stream>>>(count);
    lee_classify<<<blocksA, BLOCK, 0, stream>>>(x, typ, out, count, wl_idx, wl_x, cap, n);
    lee_worklist<<<8192, BLOCK, 0, stream>>>(typ, out, count, wl_idx, wl_x, cap, n);
}